// Round 1
// baseline (8100.832 us; speedup 1.0000x reference)
//
#include <hip/hip_runtime.h>
#include <cstddef>

#define NN 100000
#define NE 1600000
#define D 128
#define D2 256
#define EF 7
#define NL 5
#define BN_EPS 1e-5f

__device__ __forceinline__ void atomAddF(float* p, float v) { unsafeAtomicAdd(p, v); }

// ---------------- edge kernel: agg[dst] += relu(h[src] + edge_attr@We + be) ----------------
// one wave per edge; lane covers dims {2*lane, 2*lane+1}
template<int L0>
__global__ __launch_bounds__(256)
void edge_kernel(const int* __restrict__ ei, const float* __restrict__ ea,
                 const float* __restrict__ We, const float* __restrict__ be,
                 const float* __restrict__ prev, const float* __restrict__ aff,
                 const float* __restrict__ h0, float* __restrict__ agg)
{
    __shared__ __align__(16) float sWe[EF * D];
    __shared__ __align__(16) float sbe[D];
    __shared__ __align__(16) float sAC[2 * D];
    __shared__ __align__(16) float sH0[D];
    for (int i = threadIdx.x; i < EF * D; i += 256) sWe[i] = We[i];
    if (threadIdx.x < D) {
        sbe[threadIdx.x] = be[threadIdx.x];
        if (L0) sH0[threadIdx.x] = h0[threadIdx.x];
        else { sAC[threadIdx.x] = aff[threadIdx.x]; sAC[D + threadIdx.x] = aff[D + threadIdx.x]; }
    }
    __syncthreads();
    const int lane = threadIdx.x & 63;
    const int wid = (blockIdx.x * 256 + threadIdx.x) >> 6;
    const int nw = gridDim.x * 4;
    const float2* sWe2 = (const float2*)sWe;
    const float2* sbe2 = (const float2*)sbe;
    const float2* sA2 = (const float2*)sAC;
    const float2* sC2 = (const float2*)(sAC + D);
    const float2* sH02 = (const float2*)sH0;

    for (int e = wid; e < NE; e += nw) {
        const int src = ei[e];
        const int dst = ei[NE + e];
        float eav[EF];
        #pragma unroll
        for (int k = 0; k < EF; ++k) eav[k] = ea[e * EF + k];
        float2 acc = sbe2[lane];
        #pragma unroll
        for (int k = 0; k < EF; ++k) {
            const float2 w = sWe2[k * 64 + lane];
            acc.x = fmaf(eav[k], w.x, acc.x);
            acc.y = fmaf(eav[k], w.y, acc.y);
        }
        float2 h;
        if (L0) {
            h = sH02[lane];
        } else {
            const float2 v = *(const float2*)&prev[src * D + 2 * lane];
            const float2 a = sA2[lane];
            const float2 c = sC2[lane];
            h.x = fmaxf(fmaf(a.x, v.x, c.x), 0.f);
            h.y = fmaxf(fmaf(a.y, v.y, c.y), 0.f);
        }
        const float mx = fmaxf(h.x + acc.x, 0.f);
        const float my = fmaxf(h.y + acc.y, 0.f);
        float* ap = &agg[(size_t)dst * D + 2 * lane];
        if (mx != 0.f) atomAddF(ap, mx);
        if (my != 0.f) atomAddF(ap + 1, my);
    }
}

// ---------------- GEMM1: z1 = out @ W1 + b1, out = (1+eps)*h_aff + agg ----------------
// 64-row x 256-col tile per block, 256 threads, 8x8 register blocking, K chunked by 64.
#define S1 68
template<int L0>
__global__ __launch_bounds__(256, 2)
void gemm1_kernel(const float* __restrict__ prev, const float* __restrict__ aff,
                  const float* __restrict__ h0, const float* __restrict__ agg,
                  const float* __restrict__ W1, const float* __restrict__ b1,
                  const float* __restrict__ epsp,
                  float* __restrict__ z1, float* __restrict__ stats)
{
    __shared__ __align__(16) float sA[64 * S1];
    const int t = threadIdx.x;
    const int i0 = blockIdx.x * 64;
    const int cg = t & 31, rg = t >> 5;
    const int d0 = cg * 8, r0 = rg * 8;
    float acc[8][8];
    #pragma unroll
    for (int a = 0; a < 8; ++a)
        #pragma unroll
        for (int b = 0; b < 8; ++b) acc[a][b] = 0.f;
    const float epsv = 1.0f + *epsp;

    for (int kc = 0; kc < 2; ++kc) {
        const int kcb = kc * 64;
        __syncthreads();
        #pragma unroll
        for (int it = 0; it < 4; ++it) {
            const int linear = it * 1024 + t * 4;
            const int row = linear >> 6;
            const int kk = linear & 63;
            const int i = i0 + row;
            float vals[4] = {0.f, 0.f, 0.f, 0.f};
            if (i < NN) {
                const float4 g = *(const float4*)&agg[i * D + kcb + kk];
                const float gv[4] = {g.x, g.y, g.z, g.w};
                if (L0) {
                    #pragma unroll
                    for (int j = 0; j < 4; ++j)
                        vals[j] = fmaf(epsv, h0[kcb + kk + j], gv[j]);
                } else {
                    const float4 p = *(const float4*)&prev[i * D + kcb + kk];
                    const float pv[4] = {p.x, p.y, p.z, p.w};
                    #pragma unroll
                    for (int j = 0; j < 4; ++j) {
                        const float a = aff[kcb + kk + j];
                        const float c = aff[D + kcb + kk + j];
                        const float hv = fmaxf(fmaf(a, pv[j], c), 0.f);
                        vals[j] = fmaf(epsv, hv, gv[j]);
                    }
                }
            }
            #pragma unroll
            for (int j = 0; j < 4; ++j) sA[(kk + j) * S1 + row] = vals[j];
        }
        __syncthreads();
        const float* Wp = &W1[kcb * D2 + d0];
        #pragma unroll 4
        for (int k = 0; k < 64; ++k) {
            const float4 w0 = *(const float4*)&Wp[k * D2];
            const float4 w1 = *(const float4*)&Wp[k * D2 + 4];
            const float4 a0 = *(const float4*)&sA[k * S1 + r0];
            const float4 a1 = *(const float4*)&sA[k * S1 + r0 + 4];
            const float av[8] = {a0.x, a0.y, a0.z, a0.w, a1.x, a1.y, a1.z, a1.w};
            const float wv[8] = {w0.x, w0.y, w0.z, w0.w, w1.x, w1.y, w1.z, w1.w};
            #pragma unroll
            for (int rr = 0; rr < 8; ++rr)
                #pragma unroll
                for (int cc = 0; cc < 8; ++cc)
                    acc[rr][cc] = fmaf(av[rr], wv[cc], acc[rr][cc]);
        }
    }
    float bsum[8], bsq[8];
    #pragma unroll
    for (int cc = 0; cc < 8; ++cc) { bsum[cc] = 0.f; bsq[cc] = 0.f; }
    #pragma unroll
    for (int rr = 0; rr < 8; ++rr) {
        const int i = i0 + r0 + rr;
        if (i < NN) {
            float v[8];
            #pragma unroll
            for (int cc = 0; cc < 8; ++cc) {
                v[cc] = acc[rr][cc] + b1[d0 + cc];
                bsum[cc] += v[cc];
                bsq[cc] = fmaf(v[cc], v[cc], bsq[cc]);
            }
            const float4 o0 = {v[0], v[1], v[2], v[3]};
            const float4 o1 = {v[4], v[5], v[6], v[7]};
            *(float4*)&z1[i * D2 + d0] = o0;
            *(float4*)&z1[i * D2 + d0 + 4] = o1;
        }
    }
    __syncthreads();
    #pragma unroll
    for (int cc = 0; cc < 8; ++cc) {
        sA[rg * D2 + d0 + cc] = bsum[cc];
        sA[2048 + rg * D2 + d0 + cc] = bsq[cc];
    }
    __syncthreads();
    float s = 0.f, q = 0.f;
    #pragma unroll
    for (int r = 0; r < 8; ++r) { s += sA[r * D2 + t]; q += sA[2048 + r * D2 + t]; }
    atomAddF(&stats[t], s);
    atomAddF(&stats[D2 + t], q);
}

// ---------------- GEMM2: z2 = relu(a1*z1+c1) @ W2 + b2 ----------------
// 128-row x 128-col tile per block, 256 threads, 8x8 blocking, K=256 chunked by 64.
#define S2 132
__global__ __launch_bounds__(256, 2)
void gemm2_kernel(const float* __restrict__ z1, const float* __restrict__ aff1,
                  const float* __restrict__ W2, const float* __restrict__ b2,
                  float* __restrict__ outz, float* __restrict__ stats)
{
    __shared__ __align__(16) float sA[64 * S2];
    const int t = threadIdx.x;
    const int i0 = blockIdx.x * 128;
    const int cg = t & 15, rg = t >> 4;
    const int d0 = cg * 8, r0 = rg * 8;
    float acc[8][8];
    #pragma unroll
    for (int a = 0; a < 8; ++a)
        #pragma unroll
        for (int b = 0; b < 8; ++b) acc[a][b] = 0.f;

    for (int kc = 0; kc < 4; ++kc) {
        const int kcb = kc * 64;
        __syncthreads();
        #pragma unroll
        for (int it = 0; it < 8; ++it) {
            const int linear = it * 1024 + t * 4;
            const int row = linear >> 6;
            const int kk = linear & 63;
            const int i = i0 + row;
            float vals[4] = {0.f, 0.f, 0.f, 0.f};
            if (i < NN) {
                const float4 z = *(const float4*)&z1[i * D2 + kcb + kk];
                const float zv[4] = {z.x, z.y, z.z, z.w};
                #pragma unroll
                for (int j = 0; j < 4; ++j) {
                    const float a = aff1[kcb + kk + j];
                    const float c = aff1[D2 + kcb + kk + j];
                    vals[j] = fmaxf(fmaf(a, zv[j], c), 0.f);
                }
            }
            #pragma unroll
            for (int j = 0; j < 4; ++j) sA[(kk + j) * S2 + row] = vals[j];
        }
        __syncthreads();
        const float* Wp = &W2[kcb * D + d0];
        #pragma unroll 4
        for (int k = 0; k < 64; ++k) {
            const float4 w0 = *(const float4*)&Wp[k * D];
            const float4 w1 = *(const float4*)&Wp[k * D + 4];
            const float4 a0 = *(const float4*)&sA[k * S2 + r0];
            const float4 a1 = *(const float4*)&sA[k * S2 + r0 + 4];
            const float av[8] = {a0.x, a0.y, a0.z, a0.w, a1.x, a1.y, a1.z, a1.w};
            const float wv[8] = {w0.x, w0.y, w0.z, w0.w, w1.x, w1.y, w1.z, w1.w};
            #pragma unroll
            for (int rr = 0; rr < 8; ++rr)
                #pragma unroll
                for (int cc = 0; cc < 8; ++cc)
                    acc[rr][cc] = fmaf(av[rr], wv[cc], acc[rr][cc]);
        }
    }
    float bsum[8], bsq[8];
    #pragma unroll
    for (int cc = 0; cc < 8; ++cc) { bsum[cc] = 0.f; bsq[cc] = 0.f; }
    #pragma unroll
    for (int rr = 0; rr < 8; ++rr) {
        const int i = i0 + r0 + rr;
        if (i < NN) {
            float v[8];
            #pragma unroll
            for (int cc = 0; cc < 8; ++cc) {
                v[cc] = acc[rr][cc] + b2[d0 + cc];
                bsum[cc] += v[cc];
                bsq[cc] = fmaf(v[cc], v[cc], bsq[cc]);
            }
            const float4 o0 = {v[0], v[1], v[2], v[3]};
            const float4 o1 = {v[4], v[5], v[6], v[7]};
            *(float4*)&outz[i * D + d0] = o0;
            *(float4*)&outz[i * D + d0 + 4] = o1;
        }
    }
    __syncthreads();
    #pragma unroll
    for (int cc = 0; cc < 8; ++cc) {
        sA[rg * D + d0 + cc] = bsum[cc];
        sA[2048 + rg * D + d0 + cc] = bsq[cc];
    }
    __syncthreads();
    if (t < D) {
        float s = 0.f, q = 0.f;
        #pragma unroll
        for (int r = 0; r < 16; ++r) { s += sA[r * D + t]; q += sA[2048 + r * D + t]; }
        atomAddF(&stats[t], s);
        atomAddF(&stats[D + t], q);
    }
}

// ---------------- per-column BN affine coefficients ----------------
__global__ void affine_kernel(const float* __restrict__ stats, const float* __restrict__ g,
                              const float* __restrict__ bt, float* __restrict__ aff, int n)
{
    const int t = threadIdx.x;
    if (t < n) {
        const float inv = 1.0f / (float)NN;
        const float mu = stats[t] * inv;
        const float var = fmaf(-mu, mu, stats[n + t] * inv);
        const float a = g[t] * rsqrtf(var + BN_EPS);
        aff[t] = a;
        aff[n + t] = fmaf(-a, mu, bt[t]);
    }
}

// ---------------- final: out = a*z + c (no relu) ----------------
__global__ __launch_bounds__(256)
void final_kernel(const float* __restrict__ z, const float* __restrict__ aff,
                  float* __restrict__ out)
{
    const int idx = blockIdx.x * 256 + threadIdx.x;  // float4 index
    if (idx < NN * D / 4) {
        const int d0 = (idx * 4) & (D - 1);
        const float4 v = *(const float4*)&z[idx * 4];
        float4 o;
        o.x = fmaf(aff[d0 + 0], v.x, aff[D + d0 + 0]);
        o.y = fmaf(aff[d0 + 1], v.y, aff[D + d0 + 1]);
        o.z = fmaf(aff[d0 + 2], v.z, aff[D + d0 + 2]);
        o.w = fmaf(aff[d0 + 3], v.w, aff[D + d0 + 3]);
        *(float4*)&out[idx * 4] = o;
    }
}

extern "C" void kernel_launch(void* const* d_in, const int* in_sizes, int n_in,
                              void* d_out, int out_size, void* d_ws, size_t ws_size,
                              hipStream_t stream)
{
    (void)in_sizes; (void)n_in; (void)out_size; (void)ws_size;
    const int*   ei       = (const int*)d_in[1];
    const float* ea       = (const float*)d_in[2];
    const float* node_emb = (const float*)d_in[3];
    const float* We       = (const float*)d_in[4];
    const float* be       = (const float*)d_in[5];
    const float* eps      = (const float*)d_in[6];
    const float* W1       = (const float*)d_in[7];
    const float* b1       = (const float*)d_in[8];
    const float* g1       = (const float*)d_in[9];
    const float* bt1      = (const float*)d_in[10];
    const float* W2       = (const float*)d_in[11];
    const float* b2       = (const float*)d_in[12];
    const float* gbn      = (const float*)d_in[13];
    const float* bbn      = (const float*)d_in[14];
    float* out = (float*)d_out;

    float* ws     = (float*)d_ws;
    float* agg    = ws;                              // NN*D
    float* z1     = agg + (size_t)NN * D;            // NN*D2
    float* zA     = z1 + (size_t)NN * D2;            // NN*D
    float* stats1 = zA + (size_t)NN * D;             // 2*D2
    float* stats2 = stats1 + 2 * D2;                 // 2*D
    float* aff1   = stats2 + 2 * D;                  // 2*D2
    float* aff2   = aff1 + 2 * D2;                   // 2*D

    const float* prev = nullptr;
    for (int l = 0; l < NL; ++l) {
        float* dst = (l & 1) ? out : zA;
        hipMemsetAsync(agg, 0, (size_t)NN * D * sizeof(float), stream);
        hipMemsetAsync(stats1, 0, 2 * D2 * sizeof(float), stream);
        hipMemsetAsync(stats2, 0, 2 * D * sizeof(float), stream);
        if (l == 0) {
            edge_kernel<1><<<2048, 256, 0, stream>>>(ei, ea, We + l * EF * D, be + l * D,
                                                     nullptr, aff2, node_emb, agg);
            gemm1_kernel<1><<<1563, 256, 0, stream>>>(nullptr, aff2, node_emb, agg,
                                                      W1 + (size_t)l * D * D2, b1 + l * D2,
                                                      eps + l, z1, stats1);
        } else {
            edge_kernel<0><<<2048, 256, 0, stream>>>(ei, ea, We + l * EF * D, be + l * D,
                                                     prev, aff2, node_emb, agg);
            gemm1_kernel<0><<<1563, 256, 0, stream>>>(prev, aff2, node_emb, agg,
                                                      W1 + (size_t)l * D * D2, b1 + l * D2,
                                                      eps + l, z1, stats1);
        }
        affine_kernel<<<1, 256, 0, stream>>>(stats1, g1 + l * D2, bt1 + l * D2, aff1, D2);
        gemm2_kernel<<<782, 256, 0, stream>>>(z1, aff1, W2 + (size_t)l * D2 * D, b2 + l * D,
                                              dst, stats2);
        affine_kernel<<<1, 256, 0, stream>>>(stats2, gbn + l * D, bbn + l * D, aff2, D);
        prev = dst;
    }
    final_kernel<<<(NN * D / 4 + 255) / 256, 256, 0, stream>>>(prev, aff2, out);
}

// Round 2
// 2955.643 us; speedup vs baseline: 2.7408x; 2.7408x over previous
//
#include <hip/hip_runtime.h>
#include <cstddef>

#define NN 100000
#define NE 1600000
#define D 128
#define D2 256
#define EF 7
#define NL 5
#define BN_EPS 1e-5f

__device__ __forceinline__ void atomAddF(float* p, float v) { unsafeAtomicAdd(p, v); }

// ---------------- CSR build: histogram of dst ----------------
__global__ __launch_bounds__(256)
void hist_kernel(const int* __restrict__ ei, int* __restrict__ counts)
{
    const int e = blockIdx.x * 256 + threadIdx.x;
    if (e < NE) atomicAdd(&counts[ei[NE + e]], 1);
}

// single-block exclusive scan of counts[NN] -> offs[NN+1]
__global__ __launch_bounds__(1024)
void scan_kernel(const int* __restrict__ counts, int* __restrict__ offs)
{
    __shared__ int ssum[1024];
    const int t = threadIdx.x;
    const int per = (NN + 1023) / 1024;  // 98
    const int base = t * per;
    int local = 0;
    for (int j = 0; j < per; ++j) {
        const int i = base + j;
        if (i < NN) local += counts[i];
    }
    ssum[t] = local;
    __syncthreads();
    for (int off = 1; off < 1024; off <<= 1) {
        int v = 0;
        if (t >= off) v = ssum[t - off];
        __syncthreads();
        ssum[t] += v;
        __syncthreads();
    }
    int run = ssum[t] - local;  // exclusive prefix of this thread's chunk
    for (int j = 0; j < per; ++j) {
        const int i = base + j;
        if (i < NN) { offs[i] = run; run += counts[i]; }
    }
    if (t == 1023) offs[NN] = NE;
}

// scatter edges into dst-sorted order
__global__ __launch_bounds__(256)
void scatter_kernel(const int* __restrict__ ei, int* __restrict__ offmut,
                    int* __restrict__ sEid, int* __restrict__ sSrc)
{
    const int e = blockIdx.x * 256 + threadIdx.x;
    if (e < NE) {
        const int dst = ei[NE + e];
        const int pos = atomicAdd(&offmut[dst], 1);
        sEid[pos] = e;
        sSrc[pos] = ei[e];
    }
}

// ---------------- gather: xin[n] = (1+eps)*h(n) + sum_e relu(h(src)+ee) ----------------
// one wave per dst node; lane covers dims {2*lane, 2*lane+1}
template<int L0>
__global__ __launch_bounds__(256)
void gather_kernel(const int* __restrict__ offs, const int* __restrict__ sEid,
                   const int* __restrict__ sSrc, const float* __restrict__ ea,
                   const float* __restrict__ We, const float* __restrict__ be,
                   const float* __restrict__ prev, const float* __restrict__ aff,
                   const float* __restrict__ h0, const float* __restrict__ epsp,
                   float* __restrict__ xin)
{
    __shared__ __align__(16) float sWe[EF * D];
    __shared__ __align__(16) float sbe[D];
    __shared__ __align__(16) float sAC[2 * D];
    __shared__ __align__(16) float sH0[D];
    for (int i = threadIdx.x; i < EF * D; i += 256) sWe[i] = We[i];
    if (threadIdx.x < D) {
        sbe[threadIdx.x] = be[threadIdx.x];
        if (L0) sH0[threadIdx.x] = h0[threadIdx.x];
        else { sAC[threadIdx.x] = aff[threadIdx.x]; sAC[D + threadIdx.x] = aff[D + threadIdx.x]; }
    }
    __syncthreads();
    const int lane = threadIdx.x & 63;
    const int wid = (blockIdx.x * 256 + threadIdx.x) >> 6;
    if (wid >= NN) return;
    const int n = wid;
    const float2* sWe2 = (const float2*)sWe;
    const float2 bev = ((const float2*)sbe)[lane];
    float2 av = {0.f, 0.f}, cv = {0.f, 0.f}, h0v = {0.f, 0.f};
    if (L0) h0v = ((const float2*)sH0)[lane];
    else { av = ((const float2*)sAC)[lane]; cv = ((const float2*)(sAC + D))[lane]; }

    const int s = offs[n], en = offs[n + 1];
    float2 acc = {0.f, 0.f};
    int eid = 0, src = 0;
    if (s < en) { eid = sEid[s]; src = sSrc[s]; }
    for (int p = s; p < en; ++p) {
        int neid = 0, nsrc = 0;
        if (p + 1 < en) { neid = sEid[p + 1]; nsrc = sSrc[p + 1]; }
        const float* eap = &ea[(size_t)eid * EF];
        float ev[EF];
        #pragma unroll
        for (int k = 0; k < EF; ++k) ev[k] = eap[k];
        float2 m = bev;
        #pragma unroll
        for (int k = 0; k < EF; ++k) {
            const float2 w = sWe2[k * 64 + lane];
            m.x = fmaf(ev[k], w.x, m.x);
            m.y = fmaf(ev[k], w.y, m.y);
        }
        float2 h;
        if (L0) {
            h = h0v;
        } else {
            const float2 v = *(const float2*)&prev[(size_t)src * D + 2 * lane];
            h.x = fmaxf(fmaf(av.x, v.x, cv.x), 0.f);
            h.y = fmaxf(fmaf(av.y, v.y, cv.y), 0.f);
        }
        acc.x += fmaxf(h.x + m.x, 0.f);
        acc.y += fmaxf(h.y + m.y, 0.f);
        eid = neid; src = nsrc;
    }
    // self term
    float2 hs;
    if (L0) {
        hs = h0v;
    } else {
        const float2 v = *(const float2*)&prev[(size_t)n * D + 2 * lane];
        hs.x = fmaxf(fmaf(av.x, v.x, cv.x), 0.f);
        hs.y = fmaxf(fmaf(av.y, v.y, cv.y), 0.f);
    }
    const float epsv = 1.0f + *epsp;
    acc.x = fmaf(epsv, hs.x, acc.x);
    acc.y = fmaf(epsv, hs.y, acc.y);
    *(float2*)&xin[(size_t)n * D + 2 * lane] = acc;
}

// ---------------- GEMM1: z1 = xin @ W1 + b1, fused column stats ----------------
// 64-row x 256-col tile per block, 256 threads, 8x8 register blocking, K chunked by 64.
#define S1 68
__global__ __launch_bounds__(256, 2)
void gemm1_kernel(const float* __restrict__ xin,
                  const float* __restrict__ W1, const float* __restrict__ b1,
                  float* __restrict__ z1, float* __restrict__ stats)
{
    __shared__ __align__(16) float sA[64 * S1];
    const int t = threadIdx.x;
    const int i0 = blockIdx.x * 64;
    const int cg = t & 31, rg = t >> 5;
    const int d0 = cg * 8, r0 = rg * 8;
    float acc[8][8];
    #pragma unroll
    for (int a = 0; a < 8; ++a)
        #pragma unroll
        for (int b = 0; b < 8; ++b) acc[a][b] = 0.f;

    for (int kc = 0; kc < 2; ++kc) {
        const int kcb = kc * 64;
        __syncthreads();
        #pragma unroll
        for (int it = 0; it < 4; ++it) {
            const int linear = it * 1024 + t * 4;
            const int row = linear >> 6;
            const int kk = linear & 63;
            const int i = i0 + row;
            float vals[4] = {0.f, 0.f, 0.f, 0.f};
            if (i < NN) {
                const float4 g = *(const float4*)&xin[(size_t)i * D + kcb + kk];
                vals[0] = g.x; vals[1] = g.y; vals[2] = g.z; vals[3] = g.w;
            }
            #pragma unroll
            for (int j = 0; j < 4; ++j) sA[(kk + j) * S1 + row] = vals[j];
        }
        __syncthreads();
        const float* Wp = &W1[kcb * D2 + d0];
        #pragma unroll 4
        for (int k = 0; k < 64; ++k) {
            const float4 w0 = *(const float4*)&Wp[k * D2];
            const float4 w1 = *(const float4*)&Wp[k * D2 + 4];
            const float4 a0 = *(const float4*)&sA[k * S1 + r0];
            const float4 a1 = *(const float4*)&sA[k * S1 + r0 + 4];
            const float av[8] = {a0.x, a0.y, a0.z, a0.w, a1.x, a1.y, a1.z, a1.w};
            const float wv[8] = {w0.x, w0.y, w0.z, w0.w, w1.x, w1.y, w1.z, w1.w};
            #pragma unroll
            for (int rr = 0; rr < 8; ++rr)
                #pragma unroll
                for (int cc = 0; cc < 8; ++cc)
                    acc[rr][cc] = fmaf(av[rr], wv[cc], acc[rr][cc]);
        }
    }
    float bsum[8], bsq[8];
    #pragma unroll
    for (int cc = 0; cc < 8; ++cc) { bsum[cc] = 0.f; bsq[cc] = 0.f; }
    #pragma unroll
    for (int rr = 0; rr < 8; ++rr) {
        const int i = i0 + r0 + rr;
        if (i < NN) {
            float v[8];
            #pragma unroll
            for (int cc = 0; cc < 8; ++cc) {
                v[cc] = acc[rr][cc] + b1[d0 + cc];
                bsum[cc] += v[cc];
                bsq[cc] = fmaf(v[cc], v[cc], bsq[cc]);
            }
            const float4 o0 = {v[0], v[1], v[2], v[3]};
            const float4 o1 = {v[4], v[5], v[6], v[7]};
            *(float4*)&z1[(size_t)i * D2 + d0] = o0;
            *(float4*)&z1[(size_t)i * D2 + d0 + 4] = o1;
        }
    }
    __syncthreads();
    #pragma unroll
    for (int cc = 0; cc < 8; ++cc) {
        sA[rg * D2 + d0 + cc] = bsum[cc];
        sA[2048 + rg * D2 + d0 + cc] = bsq[cc];
    }
    __syncthreads();
    float s = 0.f, q = 0.f;
    #pragma unroll
    for (int r = 0; r < 8; ++r) { s += sA[r * D2 + t]; q += sA[2048 + r * D2 + t]; }
    atomAddF(&stats[t], s);
    atomAddF(&stats[D2 + t], q);
}

// ---------------- GEMM2: z2 = relu(a1*z1+c1) @ W2 + b2, fused column stats ----------------
#define S2 132
__global__ __launch_bounds__(256, 2)
void gemm2_kernel(const float* __restrict__ z1, const float* __restrict__ aff1,
                  const float* __restrict__ W2, const float* __restrict__ b2,
                  float* __restrict__ outz, float* __restrict__ stats)
{
    __shared__ __align__(16) float sA[64 * S2];
    const int t = threadIdx.x;
    const int i0 = blockIdx.x * 128;
    const int cg = t & 15, rg = t >> 4;
    const int d0 = cg * 8, r0 = rg * 8;
    float acc[8][8];
    #pragma unroll
    for (int a = 0; a < 8; ++a)
        #pragma unroll
        for (int b = 0; b < 8; ++b) acc[a][b] = 0.f;

    for (int kc = 0; kc < 4; ++kc) {
        const int kcb = kc * 64;
        __syncthreads();
        #pragma unroll
        for (int it = 0; it < 8; ++it) {
            const int linear = it * 1024 + t * 4;
            const int row = linear >> 6;
            const int kk = linear & 63;
            const int i = i0 + row;
            float vals[4] = {0.f, 0.f, 0.f, 0.f};
            if (i < NN) {
                const float4 z = *(const float4*)&z1[(size_t)i * D2 + kcb + kk];
                const float zv[4] = {z.x, z.y, z.z, z.w};
                #pragma unroll
                for (int j = 0; j < 4; ++j) {
                    const float a = aff1[kcb + kk + j];
                    const float c = aff1[D2 + kcb + kk + j];
                    vals[j] = fmaxf(fmaf(a, zv[j], c), 0.f);
                }
            }
            #pragma unroll
            for (int j = 0; j < 4; ++j) sA[(kk + j) * S2 + row] = vals[j];
        }
        __syncthreads();
        const float* Wp = &W2[kcb * D + d0];
        #pragma unroll 4
        for (int k = 0; k < 64; ++k) {
            const float4 w0 = *(const float4*)&Wp[k * D];
            const float4 w1 = *(const float4*)&Wp[k * D + 4];
            const float4 a0 = *(const float4*)&sA[k * S2 + r0];
            const float4 a1 = *(const float4*)&sA[k * S2 + r0 + 4];
            const float av[8] = {a0.x, a0.y, a0.z, a0.w, a1.x, a1.y, a1.z, a1.w};
            const float wv[8] = {w0.x, w0.y, w0.z, w0.w, w1.x, w1.y, w1.z, w1.w};
            #pragma unroll
            for (int rr = 0; rr < 8; ++rr)
                #pragma unroll
                for (int cc = 0; cc < 8; ++cc)
                    acc[rr][cc] = fmaf(av[rr], wv[cc], acc[rr][cc]);
        }
    }
    float bsum[8], bsq[8];
    #pragma unroll
    for (int cc = 0; cc < 8; ++cc) { bsum[cc] = 0.f; bsq[cc] = 0.f; }
    #pragma unroll
    for (int rr = 0; rr < 8; ++rr) {
        const int i = i0 + r0 + rr;
        if (i < NN) {
            float v[8];
            #pragma unroll
            for (int cc = 0; cc < 8; ++cc) {
                v[cc] = acc[rr][cc] + b2[d0 + cc];
                bsum[cc] += v[cc];
                bsq[cc] = fmaf(v[cc], v[cc], bsq[cc]);
            }
            const float4 o0 = {v[0], v[1], v[2], v[3]};
            const float4 o1 = {v[4], v[5], v[6], v[7]};
            *(float4*)&outz[(size_t)i * D + d0] = o0;
            *(float4*)&outz[(size_t)i * D + d0 + 4] = o1;
        }
    }
    __syncthreads();
    #pragma unroll
    for (int cc = 0; cc < 8; ++cc) {
        sA[rg * D + d0 + cc] = bsum[cc];
        sA[2048 + rg * D + d0 + cc] = bsq[cc];
    }
    __syncthreads();
    if (t < D) {
        float s = 0.f, q = 0.f;
        #pragma unroll
        for (int r = 0; r < 16; ++r) { s += sA[r * D + t]; q += sA[2048 + r * D + t]; }
        atomAddF(&stats[t], s);
        atomAddF(&stats[D + t], q);
    }
}

// ---------------- per-column BN affine coefficients ----------------
__global__ void affine_kernel(const float* __restrict__ stats, const float* __restrict__ g,
                              const float* __restrict__ bt, float* __restrict__ aff, int n)
{
    const int t = threadIdx.x;
    if (t < n) {
        const float inv = 1.0f / (float)NN;
        const float mu = stats[t] * inv;
        const float var = fmaf(-mu, mu, stats[n + t] * inv);
        const float a = g[t] * rsqrtf(var + BN_EPS);
        aff[t] = a;
        aff[n + t] = fmaf(-a, mu, bt[t]);
    }
}

// ---------------- final: out = a*z + c (no relu), in-place safe ----------------
__global__ __launch_bounds__(256)
void final_kernel(const float* __restrict__ z, const float* __restrict__ aff,
                  float* __restrict__ out)
{
    const int idx = blockIdx.x * 256 + threadIdx.x;  // float4 index
    if (idx < NN * D / 4) {
        const int d0 = (idx * 4) & (D - 1);
        const float4 v = *(const float4*)&z[idx * 4];
        float4 o;
        o.x = fmaf(aff[d0 + 0], v.x, aff[D + d0 + 0]);
        o.y = fmaf(aff[d0 + 1], v.y, aff[D + d0 + 1]);
        o.z = fmaf(aff[d0 + 2], v.z, aff[D + d0 + 2]);
        o.w = fmaf(aff[d0 + 3], v.w, aff[D + d0 + 3]);
        *(float4*)&out[idx * 4] = o;
    }
}

extern "C" void kernel_launch(void* const* d_in, const int* in_sizes, int n_in,
                              void* d_out, int out_size, void* d_ws, size_t ws_size,
                              hipStream_t stream)
{
    (void)in_sizes; (void)n_in; (void)out_size; (void)ws_size;
    const int*   ei       = (const int*)d_in[1];
    const float* ea       = (const float*)d_in[2];
    const float* node_emb = (const float*)d_in[3];
    const float* We       = (const float*)d_in[4];
    const float* be       = (const float*)d_in[5];
    const float* eps      = (const float*)d_in[6];
    const float* W1       = (const float*)d_in[7];
    const float* b1       = (const float*)d_in[8];
    const float* g1       = (const float*)d_in[9];
    const float* bt1      = (const float*)d_in[10];
    const float* W2       = (const float*)d_in[11];
    const float* b2       = (const float*)d_in[12];
    const float* gbn      = (const float*)d_in[13];
    const float* bbn      = (const float*)d_in[14];
    float* out = (float*)d_out;

    float* ws     = (float*)d_ws;
    float* xin    = ws;                               // NN*D
    float* z1     = xin + (size_t)NN * D;             // NN*D2
    float* stats1 = z1 + (size_t)NN * D2;             // 2*D2
    float* stats2 = stats1 + 2 * D2;                  // 2*D
    float* aff1   = stats2 + 2 * D;                   // 2*D2
    float* aff2   = aff1 + 2 * D2;                    // 2*D
    int*   counts = (int*)(aff2 + 2 * D);             // NN+1
    int*   offs   = counts + (NN + 1);                // NN+1
    int*   offmut = offs + (NN + 1);                  // NN
    int*   sEid   = offmut + NN;                      // NE
    int*   sSrc   = sEid + NE;                        // NE

    // ---- CSR build (dst ordering shared by all layers) ----
    hipMemsetAsync(counts, 0, (NN + 1) * sizeof(int), stream);
    hist_kernel<<<(NE + 255) / 256, 256, 0, stream>>>(ei, counts);
    scan_kernel<<<1, 1024, 0, stream>>>(counts, offs);
    hipMemcpyAsync(offmut, offs, NN * sizeof(int), hipMemcpyDeviceToDevice, stream);
    scatter_kernel<<<(NE + 255) / 256, 256, 0, stream>>>(ei, offmut, sEid, sSrc);

    for (int l = 0; l < NL; ++l) {
        hipMemsetAsync(stats1, 0, 2 * D2 * sizeof(float), stream);
        hipMemsetAsync(stats2, 0, 2 * D * sizeof(float), stream);
        if (l == 0) {
            gather_kernel<1><<<25000, 256, 0, stream>>>(offs, sEid, sSrc, ea,
                                                        We + l * EF * D, be + l * D,
                                                        nullptr, aff2, node_emb, eps + l, xin);
        } else {
            gather_kernel<0><<<25000, 256, 0, stream>>>(offs, sEid, sSrc, ea,
                                                        We + l * EF * D, be + l * D,
                                                        out, aff2, node_emb, eps + l, xin);
        }
        gemm1_kernel<<<1563, 256, 0, stream>>>(xin, W1 + (size_t)l * D * D2, b1 + l * D2,
                                               z1, stats1);
        affine_kernel<<<1, 256, 0, stream>>>(stats1, g1 + l * D2, bt1 + l * D2, aff1, D2);
        gemm2_kernel<<<782, 256, 0, stream>>>(z1, aff1, W2 + (size_t)l * D2 * D, b2 + l * D,
                                              out, stats2);
        affine_kernel<<<1, 256, 0, stream>>>(stats2, gbn + l * D, bbn + l * D, aff2, D);
    }
    final_kernel<<<(NN * D / 4 + 255) / 256, 256, 0, stream>>>(out, aff2, out);
}

// Round 4
// 2250.492 us; speedup vs baseline: 3.5996x; 1.3133x over previous
//
#include <hip/hip_runtime.h>
#include <cstddef>

#define NN 100000
#define NE 1600000
#define D 128
#define D2 256
#define EF 7
#define NL 5
#define BN_EPS 1e-5f

typedef unsigned short ushort_t;
typedef __attribute__((ext_vector_type(8))) short bf16x8;
typedef __attribute__((ext_vector_type(4))) float f32x4;

__device__ __forceinline__ void atomAddF(float* p, float v) { unsafeAtomicAdd(p, v); }

__device__ __forceinline__ unsigned f2bf1(float f) {
    unsigned u = __builtin_bit_cast(unsigned, f);
    return (u + 0x7FFFu + ((u >> 16) & 1u)) >> 16;   // RNE
}
__device__ __forceinline__ float bf2f(unsigned s16) {
    unsigned u = s16 << 16;
    return __builtin_bit_cast(float, u);
}

// ---------------- CSR build ----------------
__global__ __launch_bounds__(256)
void hist_kernel(const int* __restrict__ ei, int* __restrict__ counts)
{
    const int e = blockIdx.x * 256 + threadIdx.x;
    if (e < NE) atomicAdd(&counts[ei[NE + e]], 1);
}

__global__ __launch_bounds__(1024)
void scan_kernel(const int* __restrict__ counts, int* __restrict__ offs)
{
    __shared__ int ssum[1024];
    const int t = threadIdx.x;
    const int per = (NN + 1023) / 1024;
    const int base = t * per;
    int local = 0;
    for (int j = 0; j < per; ++j) {
        const int i = base + j;
        if (i < NN) local += counts[i];
    }
    ssum[t] = local;
    __syncthreads();
    for (int off = 1; off < 1024; off <<= 1) {
        int v = 0;
        if (t >= off) v = ssum[t - off];
        __syncthreads();
        ssum[t] += v;
        __syncthreads();
    }
    int run = ssum[t] - local;
    for (int j = 0; j < per; ++j) {
        const int i = base + j;
        if (i < NN) { offs[i] = run; run += counts[i]; }
    }
    if (t == 1023) offs[NN] = NE;
}

// scatter edges into dst-sorted order; pack edge features as bf16x8 (7 used)
__global__ __launch_bounds__(256)
void scatter_kernel(const int* __restrict__ ei, const float* __restrict__ ea,
                    int* __restrict__ offmut, int* __restrict__ sSrc,
                    ushort_t* __restrict__ sEab)
{
    const int e = blockIdx.x * 256 + threadIdx.x;
    if (e < NE) {
        const int dst = ei[NE + e];
        const int pos = atomicAdd(&offmut[dst], 1);
        sSrc[pos] = ei[e];
        const float* eap = &ea[(size_t)e * EF];
        const unsigned o0 = f2bf1(eap[0]) | (f2bf1(eap[1]) << 16);
        const unsigned o1 = f2bf1(eap[2]) | (f2bf1(eap[3]) << 16);
        const unsigned o2 = f2bf1(eap[4]) | (f2bf1(eap[5]) << 16);
        const unsigned o3 = f2bf1(eap[6]);
        *(uint4*)&sEab[(size_t)pos * 8] = make_uint4(o0, o1, o2, o3);
    }
}

// ---------------- weight convert: W1[l][k][n]->W1t[l][n][k] bf16, W2 same ----------------
__global__ __launch_bounds__(256)
void wconv_kernel(const float* __restrict__ W1, const float* __restrict__ W2,
                  ushort_t* __restrict__ W1t, ushort_t* __restrict__ W2t)
{
    const int idx = blockIdx.x * 256 + threadIdx.x;
    const int per = D * D2;
    if (idx < NL * per) {
        const int l = idx / per, r = idx % per;
        const int k1 = r / D2, n1 = r % D2;            // W1: [128][256]
        W1t[(size_t)l * per + n1 * D + k1] = (ushort_t)f2bf1(W1[idx]);
        const int k2 = r / D, n2 = r % D;              // W2: [256][128]
        W2t[(size_t)l * per + n2 * D2 + k2] = (ushort_t)f2bf1(W2[idx]);
    }
}

// ---------------- gather: xin[n] = (1+eps)*h(n) + sum_e relu(h(src)+ee) ----------------
// fp32 output + column-sum accumulation; 4 waves/block, 4 nodes/wave (wave-stride)
#define GWAVES 25000
template<int L0>
__global__ __launch_bounds__(256)
void gather_kernel(const int* __restrict__ offs, const int* __restrict__ sSrc,
                   const ushort_t* __restrict__ sEab,
                   const float* __restrict__ We, const float* __restrict__ be,
                   const ushort_t* __restrict__ hB, const float* __restrict__ aff,
                   const float* __restrict__ h0, const float* __restrict__ epsp,
                   float* __restrict__ xinF, float* __restrict__ xsum)
{
    __shared__ __align__(16) float sWe[EF * D];
    __shared__ __align__(16) float sbe[D];
    __shared__ __align__(16) float sAC[2 * D];
    __shared__ __align__(16) float sH0[D];
    __shared__ __align__(16) float sCS[4][D];
    for (int i = threadIdx.x; i < EF * D; i += 256) sWe[i] = We[i];
    if (threadIdx.x < D) {
        sbe[threadIdx.x] = be[threadIdx.x];
        if (L0) sH0[threadIdx.x] = h0[threadIdx.x];
        else { sAC[threadIdx.x] = aff[threadIdx.x]; sAC[D + threadIdx.x] = aff[D + threadIdx.x]; }
    }
    __syncthreads();
    const int lane = threadIdx.x & 63;
    const int w = threadIdx.x >> 6;
    const int wid = blockIdx.x * 4 + w;
    const float2* sWe2 = (const float2*)sWe;
    const float2 bev = ((const float2*)sbe)[lane];
    float2 av = {0.f, 0.f}, cv = {0.f, 0.f}, h0v = {0.f, 0.f};
    if (L0) h0v = ((const float2*)sH0)[lane];
    else { av = ((const float2*)sAC)[lane]; cv = ((const float2*)(sAC + D))[lane]; }
    const float epsv = 1.0f + *epsp;

    float2 cs = {0.f, 0.f};
    for (int it = 0; it < 4; ++it) {
        const int n = wid + it * GWAVES;
        if (n >= NN) break;
        const int s = offs[n], en = offs[n + 1];
        float2 acc = {0.f, 0.f};
        for (int p = s; p < en; ++p) {
            const uint4 ev4 = *(const uint4*)&sEab[(size_t)p * 8];
            const int src = sSrc[p];
            float ev[EF];
            ev[0] = bf2f(ev4.x & 0xFFFFu); ev[1] = bf2f(ev4.x >> 16);
            ev[2] = bf2f(ev4.y & 0xFFFFu); ev[3] = bf2f(ev4.y >> 16);
            ev[4] = bf2f(ev4.z & 0xFFFFu); ev[5] = bf2f(ev4.z >> 16);
            ev[6] = bf2f(ev4.w & 0xFFFFu);
            float2 m = bev;
            #pragma unroll
            for (int k = 0; k < EF; ++k) {
                const float2 wv = sWe2[k * 64 + lane];
                m.x = fmaf(ev[k], wv.x, m.x);
                m.y = fmaf(ev[k], wv.y, m.y);
            }
            float2 h;
            if (L0) {
                h = h0v;
            } else {
                const unsigned hv = *(const unsigned*)&hB[(size_t)src * D + 2 * lane];
                const float vx = bf2f(hv & 0xFFFFu), vy = bf2f(hv >> 16);
                h.x = fmaxf(fmaf(av.x, vx, cv.x), 0.f);
                h.y = fmaxf(fmaf(av.y, vy, cv.y), 0.f);
            }
            acc.x += fmaxf(h.x + m.x, 0.f);
            acc.y += fmaxf(h.y + m.y, 0.f);
        }
        float2 hs;
        if (L0) {
            hs = h0v;
        } else {
            const unsigned hv = *(const unsigned*)&hB[(size_t)n * D + 2 * lane];
            const float vx = bf2f(hv & 0xFFFFu), vy = bf2f(hv >> 16);
            hs.x = fmaxf(fmaf(av.x, vx, cv.x), 0.f);
            hs.y = fmaxf(fmaf(av.y, vy, cv.y), 0.f);
        }
        acc.x = fmaf(epsv, hs.x, acc.x);
        acc.y = fmaf(epsv, hs.y, acc.y);
        cs.x += acc.x; cs.y += acc.y;
        *(float2*)&xinF[(size_t)n * D + 2 * lane] = acc;
    }
    sCS[w][2 * lane] = cs.x;
    sCS[w][2 * lane + 1] = cs.y;
    __syncthreads();
    if (threadIdx.x < D) {
        const float s = sCS[0][threadIdx.x] + sCS[1][threadIdx.x] +
                        sCS[2][threadIdx.x] + sCS[3][threadIdx.x];
        atomAddF(&xsum[threadIdx.x], s);
    }
}

// ---------------- mm1: z1c = (xin - colmean) @ W1 (bf16 MFMA), fused stats ----------------
// block: 64 rows x 256 cols, 4 waves (wave w -> cols w*64..+63), K=128
__global__ __launch_bounds__(256, 2)
void mm1_kernel(const float* __restrict__ xinF, const float* __restrict__ xsum,
                const ushort_t* __restrict__ W1t,
                ushort_t* __restrict__ z1B, float* __restrict__ stats)
{
    __shared__ __align__(16) ushort_t sA[64 * 128];
    __shared__ __align__(16) float sM[D];
    const int t = threadIdx.x;
    if (t < D) sM[t] = xsum[t] * (1.0f / (float)NN);
    const int i0 = blockIdx.x * 64;
    const int lane = t & 63, w = t >> 6;
    const int nb = w * 64;

    bf16x8 bfr[4][4];
    #pragma unroll
    for (int nt = 0; nt < 4; ++nt)
        #pragma unroll
        for (int ks = 0; ks < 4; ++ks) {
            const int n = nb + nt * 16 + (lane & 15);
            const int k = ks * 32 + (lane >> 4) * 8;
            bfr[nt][ks] = *(const bf16x8*)&W1t[n * D + k];
        }
    __syncthreads();   // sM visible

    #pragma unroll
    for (int p = 0; p < 4; ++p) {
        const int linear = p * 256 + t;
        const int row = linear >> 4, ch = linear & 15;
        const int gi = i0 + row;
        unsigned oo[4] = {0, 0, 0, 0};
        if (gi < NN) {
            const float4 a = *(const float4*)&xinF[(size_t)gi * D + ch * 8];
            const float4 b = *(const float4*)&xinF[(size_t)gi * D + ch * 8 + 4];
            const float vv[8] = {a.x, a.y, a.z, a.w, b.x, b.y, b.z, b.w};
            #pragma unroll
            for (int j2 = 0; j2 < 4; ++j2) {
                const int c0 = ch * 8 + j2 * 2;
                const float lo = vv[2 * j2]     - sM[c0];
                const float hi = vv[2 * j2 + 1] - sM[c0 + 1];
                oo[j2] = f2bf1(lo) | (f2bf1(hi) << 16);
            }
        }
        unsigned boff = (unsigned)(row * 256 + ch * 16);
        boff ^= (unsigned)((row & 7) << 4);
        *(uint4*)((char*)sA + boff) = make_uint4(oo[0], oo[1], oo[2], oo[3]);
    }
    __syncthreads();

    f32x4 acc[4][4];
    #pragma unroll
    for (int a = 0; a < 4; ++a)
        #pragma unroll
        for (int b = 0; b < 4; ++b) acc[a][b] = (f32x4){0.f, 0.f, 0.f, 0.f};

    #pragma unroll
    for (int mt = 0; mt < 4; ++mt) {
        bf16x8 af[4];
        #pragma unroll
        for (int ks = 0; ks < 4; ++ks) {
            const int row = mt * 16 + (lane & 15);
            unsigned boff = (unsigned)(row * 256 + ks * 64 + (lane >> 4) * 16);
            boff ^= (unsigned)((row & 7) << 4);
            af[ks] = *(const bf16x8*)((const char*)sA + boff);
        }
        #pragma unroll
        for (int nt = 0; nt < 4; ++nt)
            #pragma unroll
            for (int ks = 0; ks < 4; ++ks)
                acc[mt][nt] = __builtin_amdgcn_mfma_f32_16x16x32_bf16(af[ks], bfr[nt][ks], acc[mt][nt], 0, 0, 0);
    }

    float s[4], q[4];
    #pragma unroll
    for (int nt = 0; nt < 4; ++nt) { s[nt] = 0.f; q[nt] = 0.f; }
    #pragma unroll
    for (int nt = 0; nt < 4; ++nt) {
        const int n = nb + nt * 16 + (lane & 15);
        #pragma unroll
        for (int mt = 0; mt < 4; ++mt)
            #pragma unroll
            for (int r = 0; r < 4; ++r) {
                const int i = i0 + mt * 16 + (lane >> 4) * 4 + r;
                if (i < NN) {
                    const float v = acc[mt][nt][r];
                    s[nt] += v; q[nt] = fmaf(v, v, q[nt]);
                    z1B[(size_t)i * D2 + n] = (ushort_t)f2bf1(v);
                }
            }
    }
    #pragma unroll
    for (int nt = 0; nt < 4; ++nt) {
        s[nt] += __shfl_xor(s[nt], 16, 64); s[nt] += __shfl_xor(s[nt], 32, 64);
        q[nt] += __shfl_xor(q[nt], 16, 64); q[nt] += __shfl_xor(q[nt], 32, 64);
    }
    if (lane < 16) {
        #pragma unroll
        for (int nt = 0; nt < 4; ++nt) {
            const int n = nb + nt * 16 + lane;
            atomAddF(&stats[n], s[nt]);
            atomAddF(&stats[D2 + n], q[nt]);
        }
    }
}

// ---------------- ymean: ysum[c] = sum_rows relu(a*z1c+cc) ----------------
#define YROWS 391
__global__ __launch_bounds__(256)
void ymean_kernel(const ushort_t* __restrict__ z1B, const float* __restrict__ aff1,
                  float* __restrict__ ysum)
{
    __shared__ float sR[4][D2];
    const int t = threadIdx.x;
    const int c0 = (t & 63) * 4;
    const int rg = t >> 6;
    const float a0 = aff1[c0], a1 = aff1[c0 + 1], a2 = aff1[c0 + 2], a3 = aff1[c0 + 3];
    const float b0 = aff1[D2 + c0], b1 = aff1[D2 + c0 + 1], b2 = aff1[D2 + c0 + 2], b3 = aff1[D2 + c0 + 3];
    float s0 = 0.f, s1 = 0.f, s2 = 0.f, s3 = 0.f;
    const int rend = min(NN, (blockIdx.x + 1) * YROWS);
    for (int r = blockIdx.x * YROWS + rg; r < rend; r += 4) {
        const uint2 v = *(const uint2*)&z1B[(size_t)r * D2 + c0];
        s0 += fmaxf(fmaf(a0, bf2f(v.x & 0xFFFFu), b0), 0.f);
        s1 += fmaxf(fmaf(a1, bf2f(v.x >> 16),     b1), 0.f);
        s2 += fmaxf(fmaf(a2, bf2f(v.y & 0xFFFFu), b2), 0.f);
        s3 += fmaxf(fmaf(a3, bf2f(v.y >> 16),     b3), 0.f);
    }
    sR[rg][c0] = s0; sR[rg][c0 + 1] = s1; sR[rg][c0 + 2] = s2; sR[rg][c0 + 3] = s3;
    __syncthreads();
    if (t < D2) atomAddF(&ysum[t], sR[0][t] + sR[1][t] + sR[2][t] + sR[3][t]);
}

// ---------------- mm2: z2c = (relu(a1*z1c+c1) - ymean) @ W2 (bf16 MFMA), fused stats ----------------
// block: 64 rows x 128 cols, 4 waves (wave w -> cols w*32..+31), K=256
__global__ __launch_bounds__(256, 2)
void mm2_kernel(const ushort_t* __restrict__ z1B, const float* __restrict__ aff1,
                const float* __restrict__ ysum, const ushort_t* __restrict__ W2t,
                ushort_t* __restrict__ hB, float* __restrict__ stats)
{
    __shared__ __align__(16) ushort_t sA[64 * 256];
    __shared__ __align__(16) float sAff[2 * D2];
    __shared__ __align__(16) float sYm[D2];
    const int t = threadIdx.x;
    sAff[t] = aff1[t]; sAff[t + 256] = aff1[t + 256];
    sYm[t] = ysum[t] * (1.0f / (float)NN);
    const int i0 = blockIdx.x * 64;
    const int lane = t & 63, w = t >> 6;
    const int nb = w * 32;

    bf16x8 bfr[2][8];
    #pragma unroll
    for (int nt = 0; nt < 2; ++nt)
        #pragma unroll
        for (int ks = 0; ks < 8; ++ks) {
            const int n = nb + nt * 16 + (lane & 15);
            const int k = ks * 32 + (lane >> 4) * 8;
            bfr[nt][ks] = *(const bf16x8*)&W2t[n * D2 + k];
        }
    __syncthreads();   // sAff/sYm visible

    #pragma unroll
    for (int p = 0; p < 8; ++p) {
        const int linear = p * 256 + t;
        const int row = linear >> 5, ch = linear & 31;
        const int gi = i0 + row;
        uint4 v = make_uint4(0, 0, 0, 0);
        if (gi < NN) v = *(const uint4*)&z1B[(size_t)gi * D2 + ch * 8];
        unsigned uu[4] = {v.x, v.y, v.z, v.w};
        unsigned oo[4] = {0, 0, 0, 0};
        if (gi < NN) {
            #pragma unroll
            for (int j2 = 0; j2 < 4; ++j2) {
                const int c0 = ch * 8 + j2 * 2;
                float lo = bf2f(uu[j2] & 0xFFFFu);
                float hi = bf2f(uu[j2] >> 16);
                lo = fmaxf(fmaf(sAff[c0], lo, sAff[D2 + c0]), 0.f) - sYm[c0];
                hi = fmaxf(fmaf(sAff[c0 + 1], hi, sAff[D2 + c0 + 1]), 0.f) - sYm[c0 + 1];
                oo[j2] = f2bf1(lo) | (f2bf1(hi) << 16);
            }
        }
        unsigned boff = (unsigned)(row * 512 + ch * 16);
        boff ^= (unsigned)((row & 7) << 4);
        *(uint4*)((char*)sA + boff) = make_uint4(oo[0], oo[1], oo[2], oo[3]);
    }
    __syncthreads();

    f32x4 acc[4][2];
    #pragma unroll
    for (int a = 0; a < 4; ++a)
        #pragma unroll
        for (int b = 0; b < 2; ++b) acc[a][b] = (f32x4){0.f, 0.f, 0.f, 0.f};

    #pragma unroll
    for (int mt = 0; mt < 4; ++mt) {
        bf16x8 af[8];
        #pragma unroll
        for (int ks = 0; ks < 8; ++ks) {
            const int row = mt * 16 + (lane & 15);
            unsigned boff = (unsigned)(row * 512 + ks * 64 + (lane >> 4) * 16);
            boff ^= (unsigned)((row & 7) << 4);
            af[ks] = *(const bf16x8*)((const char*)sA + boff);
        }
        #pragma unroll
        for (int nt = 0; nt < 2; ++nt)
            #pragma unroll
            for (int ks = 0; ks < 8; ++ks)
                acc[mt][nt] = __builtin_amdgcn_mfma_f32_16x16x32_bf16(af[ks], bfr[nt][ks], acc[mt][nt], 0, 0, 0);
    }

    float s[2], q[2];
    #pragma unroll
    for (int nt = 0; nt < 2; ++nt) { s[nt] = 0.f; q[nt] = 0.f; }
    #pragma unroll
    for (int nt = 0; nt < 2; ++nt) {
        const int n = nb + nt * 16 + (lane & 15);
        #pragma unroll
        for (int mt = 0; mt < 4; ++mt)
            #pragma unroll
            for (int r = 0; r < 4; ++r) {
                const int i = i0 + mt * 16 + (lane >> 4) * 4 + r;
                if (i < NN) {
                    const float v = acc[mt][nt][r];
                    s[nt] += v; q[nt] = fmaf(v, v, q[nt]);
                    hB[(size_t)i * D + n] = (ushort_t)f2bf1(v);
                }
            }
    }
    #pragma unroll
    for (int nt = 0; nt < 2; ++nt) {
        s[nt] += __shfl_xor(s[nt], 16, 64); s[nt] += __shfl_xor(s[nt], 32, 64);
        q[nt] += __shfl_xor(q[nt], 16, 64); q[nt] += __shfl_xor(q[nt], 32, 64);
    }
    if (lane < 16) {
        #pragma unroll
        for (int nt = 0; nt < 2; ++nt) {
            const int n = nb + nt * 16 + lane;
            atomAddF(&stats[n], s[nt]);
            atomAddF(&stats[D + n], q[nt]);
        }
    }
}

// ---------------- per-column BN affine coefficients ----------------
__global__ void affine_kernel(const float* __restrict__ stats, const float* __restrict__ g,
                              const float* __restrict__ bt, float* __restrict__ aff, int n)
{
    const int t = threadIdx.x;
    if (t < n) {
        const float inv = 1.0f / (float)NN;
        const float mu = stats[t] * inv;
        const float var = fmaf(-mu, mu, stats[n + t] * inv);
        const float a = g[t] * rsqrtf(var + BN_EPS);
        aff[t] = a;
        aff[n + t] = fmaf(-a, mu, bt[t]);
    }
}

// ---------------- final: out = a*h + c (fp32 out) ----------------
__global__ __launch_bounds__(256)
void final_kernel(const ushort_t* __restrict__ hB, const float* __restrict__ aff,
                  float* __restrict__ out)
{
    const int idx = blockIdx.x * 256 + threadIdx.x;  // float4 index
    if (idx < NN * D / 4) {
        const int d0 = (idx * 4) & (D - 1);
        const uint2 v = *(const uint2*)&hB[(size_t)idx * 4];
        float4 o;
        o.x = fmaf(aff[d0 + 0], bf2f(v.x & 0xFFFFu), aff[D + d0 + 0]);
        o.y = fmaf(aff[d0 + 1], bf2f(v.x >> 16),     aff[D + d0 + 1]);
        o.z = fmaf(aff[d0 + 2], bf2f(v.y & 0xFFFFu), aff[D + d0 + 2]);
        o.w = fmaf(aff[d0 + 3], bf2f(v.y >> 16),     aff[D + d0 + 3]);
        *(float4*)&out[(size_t)idx * 4] = o;
    }
}

extern "C" void kernel_launch(void* const* d_in, const int* in_sizes, int n_in,
                              void* d_out, int out_size, void* d_ws, size_t ws_size,
                              hipStream_t stream)
{
    (void)in_sizes; (void)n_in; (void)out_size; (void)ws_size;
    const int*   ei       = (const int*)d_in[1];
    const float* ea       = (const float*)d_in[2];
    const float* node_emb = (const float*)d_in[3];
    const float* We       = (const float*)d_in[4];
    const float* be       = (const float*)d_in[5];
    const float* eps      = (const float*)d_in[6];
    const float* W1       = (const float*)d_in[7];
    const float* g1       = (const float*)d_in[9];
    const float* bt1      = (const float*)d_in[10];
    const float* W2       = (const float*)d_in[11];
    const float* gbn      = (const float*)d_in[13];
    const float* bbn      = (const float*)d_in[14];
    float* out = (float*)d_out;

    char* base = (char*)d_ws;
    size_t off = 0;
    auto alloc = [&](size_t bytes) -> void* {
        void* p = base + off;
        off = (off + bytes + 255) & ~(size_t)255;
        return p;
    };
    float*    xinF   = (float*)alloc((size_t)NN * D * 4);
    ushort_t* z1B    = (ushort_t*)alloc((size_t)NN * D2 * 2);
    ushort_t* hB     = (ushort_t*)alloc((size_t)NN * D * 2);
    ushort_t* W1t    = (ushort_t*)alloc((size_t)NL * D * D2 * 2);
    ushort_t* W2t    = (ushort_t*)alloc((size_t)NL * D * D2 * 2);
    // redzone: stats1(512) stats2(256) xsum(128) ysum(256) -> one memset
    float*    red    = (float*)alloc(1152 * sizeof(float));
    float*    stats1 = red;
    float*    stats2 = red + 512;
    float*    xsum   = red + 768;
    float*    ysum   = red + 896;
    float*    aff1   = (float*)alloc(2 * D2 * sizeof(float));
    float*    aff2   = (float*)alloc(2 * D * sizeof(float));
    int*      counts = (int*)alloc((NN + 1) * sizeof(int));
    int*      offs   = (int*)alloc((NN + 1) * sizeof(int));
    int*      offmut = (int*)alloc(NN * sizeof(int));
    int*      sSrc   = (int*)alloc((size_t)NE * sizeof(int));
    ushort_t* sEab   = (ushort_t*)alloc((size_t)NE * 8 * 2);

    // ---- CSR build + weight conversion ----
    hipMemsetAsync(counts, 0, (NN + 1) * sizeof(int), stream);
    hist_kernel<<<(NE + 255) / 256, 256, 0, stream>>>(ei, counts);
    scan_kernel<<<1, 1024, 0, stream>>>(counts, offs);
    hipMemcpyAsync(offmut, offs, NN * sizeof(int), hipMemcpyDeviceToDevice, stream);
    scatter_kernel<<<(NE + 255) / 256, 256, 0, stream>>>(ei, ea, offmut, sSrc, sEab);
    wconv_kernel<<<(NL * D * D2 + 255) / 256, 256, 0, stream>>>(W1, W2, W1t, W2t);

    for (int l = 0; l < NL; ++l) {
        hipMemsetAsync(red, 0, 1152 * sizeof(float), stream);
        if (l == 0) {
            gather_kernel<1><<<6250, 256, 0, stream>>>(offs, sSrc, sEab,
                                                       We + l * EF * D, be + l * D,
                                                       hB, aff2, node_emb, eps + l, xinF, xsum);
        } else {
            gather_kernel<0><<<6250, 256, 0, stream>>>(offs, sSrc, sEab,
                                                       We + l * EF * D, be + l * D,
                                                       hB, aff2, node_emb, eps + l, xinF, xsum);
        }
        mm1_kernel<<<(NN + 63) / 64, 256, 0, stream>>>(xinF, xsum, W1t + (size_t)l * D * D2,
                                                       z1B, stats1);
        affine_kernel<<<1, 256, 0, stream>>>(stats1, g1 + l * D2, bt1 + l * D2, aff1, D2);
        ymean_kernel<<<256, 256, 0, stream>>>(z1B, aff1, ysum);
        mm2_kernel<<<(NN + 63) / 64, 256, 0, stream>>>(z1B, aff1, ysum,
                                                       W2t + (size_t)l * D * D2, hB, stats2);
        affine_kernel<<<1, 256, 0, stream>>>(stats2, gbn + l * D, bbn + l * D, aff2, D);
    }
    final_kernel<<<(NN * D / 4 + 255) / 256, 256, 0, stream>>>(hB, aff2, out);
}